// Round 1
// baseline (4220.694 us; speedup 1.0000x reference)
//
#include <hip/hip_runtime.h>

#define D_     512
#define H_     8
#define DH_    64
#define NCOLS_ 2048
#define DCOL_  22
#define B_     8
#define NKEEP_ 768
#define T_     769
#define BT_    (B_*T_)   // 6152
#define BH_    (B_*H_)   // 64

// ---------------------------------------------------------------------------
// GEMM: C = A[M,512] @ W[512,512]^T + bias
// mode 0: out[b,h,t,dh] = (v+bias)*rel[n]*0.125   (head proj; fold rel & 1/sqrt(dh))
// mode 1: out[b,h,t,dh] = v+bias                  (tail / value proj)
// mode 3: out[m*512+n]  = v+bias                  (output proj, plain layout)
// ---------------------------------------------------------------------------
__global__ __launch_bounds__(256) void gemm_proj(
    const float* __restrict__ A, const float* __restrict__ W,
    const float* __restrict__ bias, const float* __restrict__ rel,
    float* __restrict__ out, const int mode)
{
    __shared__ __align__(16) float As[16][68];
    __shared__ __align__(16) float Bs[16][68];
    const int t  = threadIdx.x;
    const int m0 = blockIdx.y * 64;
    const int n0 = blockIdx.x * 64;
    const int tm = t >> 4, tn = t & 15;
    float acc[4][4] = {};
    for (int k0 = 0; k0 < 512; k0 += 16) {
        #pragma unroll
        for (int i = 0; i < 4; ++i) {
            int idx = t + i*256;
            int mm = idx >> 4;
            int kk = idx & 15;
            int row = m0 + mm;
            As[kk][mm] = (row < BT_) ? A[(size_t)row*512 + k0 + kk] : 0.f;
            Bs[kk][mm] = W[(size_t)(n0 + mm)*512 + k0 + kk];
        }
        __syncthreads();
        #pragma unroll
        for (int kk = 0; kk < 16; ++kk) {
            float4 a4 = *(const float4*)&As[kk][tm*4];
            float4 b4 = *(const float4*)&Bs[kk][tn*4];
            float av[4] = {a4.x, a4.y, a4.z, a4.w};
            float bv[4] = {b4.x, b4.y, b4.z, b4.w};
            #pragma unroll
            for (int i = 0; i < 4; ++i)
                #pragma unroll
                for (int j = 0; j < 4; ++j)
                    acc[i][j] += av[i] * bv[j];
        }
        __syncthreads();
    }
    #pragma unroll
    for (int i = 0; i < 4; ++i) {
        int m = m0 + tm*4 + i;
        if (m >= BT_) continue;
        int b = m / T_, tt = m % T_;
        #pragma unroll
        for (int j = 0; j < 4; ++j) {
            int n = n0 + tn*4 + j;
            float v = acc[i][j] + bias[n];
            if (mode == 3) {
                out[(size_t)m*512 + n] = v;
            } else {
                if (mode == 0) v *= rel[n] * 0.125f;
                int h = n >> 6, dh = n & 63;
                out[(((size_t)b*H_ + h)*T_ + tt)*64 + dh] = v;
            }
        }
    }
}

// ---------------------------------------------------------------------------
// Normalize col_head/col_tail rows and gather per ids_keep.
// Output row (b,h,q): src = (q==0) ? 0 : 1+ids_keep[b][q-1]
// ---------------------------------------------------------------------------
__global__ void gather_norm(
    const float* __restrict__ col_head, const float* __restrict__ col_tail,
    const int* __restrict__ ids, float* __restrict__ chg, float* __restrict__ ctg)
{
    int r = blockIdx.x * blockDim.x + threadIdx.x;
    const int total = BH_ * T_;
    if (r >= 2*total) return;
    const bool tail = (r >= total);
    int rr = tail ? r - total : r;
    int bh = rr / T_;
    int q  = rr - bh*T_;
    int b  = bh >> 3, h = bh & 7;
    int src = (q == 0) ? 0 : (1 + ids[b*NKEEP_ + q - 1]);
    const float* cp = (tail ? col_tail : col_head) + ((size_t)h*NCOLS_ + src)*DCOL_;
    float v[DCOL_];
    float ss = 0.f;
    #pragma unroll
    for (int j = 0; j < DCOL_; ++j) { v[j] = cp[j]; ss += v[j]*v[j]; }
    float inv = 1.0f / sqrtf(ss);
    float* op = (tail ? ctg : chg) + (size_t)rr*DCOL_;
    #pragma unroll
    for (int j = 0; j < DCOL_; ++j) op[j] = v[j]*inv;
}

// ---------------------------------------------------------------------------
// Score: S[q,k] = dot64(fh',ft) + ((top22+bias>0 && q!=k && k!=0) ? 0 : -1e4)
// One block per 64x64 (q,k) tile per (b,h). Writes directly into fr output.
// ---------------------------------------------------------------------------
__global__ __launch_bounds__(256) void score_kernel(
    const float* __restrict__ fh, const float* __restrict__ ft,
    const float* __restrict__ chg, const float* __restrict__ ctg,
    const float* __restrict__ biasp, float* __restrict__ fr)
{
    __shared__ __align__(16) float Fh[64][68];
    __shared__ __align__(16) float Ft[64][68];
    __shared__ __align__(16) float Ch[64][24];
    __shared__ __align__(16) float Ct[64][24];
    const int bh = blockIdx.z;
    const int q0 = blockIdx.y * 64;
    const int k0 = blockIdx.x * 64;
    const int t  = threadIdx.x;
    #pragma unroll
    for (int i = 0; i < 16; ++i) {
        int idx = t + i*256;
        int r = idx >> 6, c = idx & 63;
        int q = q0 + r;
        Fh[r][c] = (q < T_) ? fh[((size_t)bh*T_ + q)*64 + c] : 0.f;
        int k = k0 + r;
        Ft[r][c] = (k < T_) ? ft[((size_t)bh*T_ + k)*64 + c] : 0.f;
    }
    for (int idx = t; idx < 64*24; idx += 256) {
        int r = idx / 24, c = idx - r*24;
        int q = q0 + r, k = k0 + r;
        Ch[r][c] = (c < DCOL_ && q < T_) ? chg[((size_t)bh*T_ + q)*DCOL_ + c] : 0.f;
        Ct[r][c] = (c < DCOL_ && k < T_) ? ctg[((size_t)bh*T_ + k)*DCOL_ + c] : 0.f;
    }
    __syncthreads();
    const int tq = t >> 4, tk = t & 15;
    float acc[4][4]  = {};
    float accT[4][4] = {};
    #pragma unroll
    for (int d0 = 0; d0 < 64; d0 += 4) {
        float4 a4[4], b4[4];
        #pragma unroll
        for (int i = 0; i < 4; ++i) a4[i] = *(const float4*)&Fh[tq*4+i][d0];
        #pragma unroll
        for (int j = 0; j < 4; ++j) b4[j] = *(const float4*)&Ft[tk*4+j][d0];
        #pragma unroll
        for (int i = 0; i < 4; ++i)
            #pragma unroll
            for (int j = 0; j < 4; ++j)
                acc[i][j] += a4[i].x*b4[j].x + a4[i].y*b4[j].y
                           + a4[i].z*b4[j].z + a4[i].w*b4[j].w;
    }
    #pragma unroll
    for (int d0 = 0; d0 < 24; d0 += 4) {
        float4 a4[4], b4[4];
        #pragma unroll
        for (int i = 0; i < 4; ++i) a4[i] = *(const float4*)&Ch[tq*4+i][d0];
        #pragma unroll
        for (int j = 0; j < 4; ++j) b4[j] = *(const float4*)&Ct[tk*4+j][d0];
        #pragma unroll
        for (int i = 0; i < 4; ++i)
            #pragma unroll
            for (int j = 0; j < 4; ++j)
                accT[i][j] += a4[i].x*b4[j].x + a4[i].y*b4[j].y
                            + a4[i].z*b4[j].z + a4[i].w*b4[j].w;
    }
    const float bias = biasp[0];
    #pragma unroll
    for (int i = 0; i < 4; ++i) {
        int q = q0 + tq*4 + i;
        if (q >= T_) continue;
        #pragma unroll
        for (int j = 0; j < 4; ++j) {
            int k = k0 + tk*4 + j;
            if (k >= T_) continue;
            bool keep = (accT[i][j] + bias > 0.f) && (q != k) && (k != 0);
            fr[((size_t)bh*T_ + q)*T_ + k] = acc[i][j] + (keep ? 0.f : -10000.f);
        }
    }
}

// ---------------------------------------------------------------------------
// Row softmax in-place on fr (one block per row, 769 elements).
// ---------------------------------------------------------------------------
__global__ __launch_bounds__(256) void softmax_kernel(float* __restrict__ fr)
{
    __shared__ float red[4];
    const int t = threadIdx.x;
    float* p = fr + (size_t)blockIdx.x * T_;
    float v[4];
    float m = -3.4e38f;
    #pragma unroll
    for (int i = 0; i < 4; ++i) {
        int idx = t + i*256;
        v[i] = (idx < T_) ? p[idx] : -3.4e38f;
        m = fmaxf(m, v[i]);
    }
    #pragma unroll
    for (int off = 32; off > 0; off >>= 1) m = fmaxf(m, __shfl_xor(m, off, 64));
    if ((t & 63) == 0) red[t >> 6] = m;
    __syncthreads();
    m = fmaxf(fmaxf(red[0], red[1]), fmaxf(red[2], red[3]));
    __syncthreads();
    float e[4]; float s = 0.f;
    #pragma unroll
    for (int i = 0; i < 4; ++i) {
        int idx = t + i*256;
        e[i] = (idx < T_) ? expf(v[i] - m) : 0.f;
        s += e[i];
    }
    #pragma unroll
    for (int off = 32; off > 0; off >>= 1) s += __shfl_xor(s, off, 64);
    if ((t & 63) == 0) red[t >> 6] = s;
    __syncthreads();
    s = red[0] + red[1] + red[2] + red[3];
    float inv = 1.0f / s;
    #pragma unroll
    for (int i = 0; i < 4; ++i) {
        int idx = t + i*256;
        if (idx < T_) p[idx] = e[i] * inv;
    }
}

// ---------------------------------------------------------------------------
// PV: x1[b,q,h*64+d] = sum_k fr[bh,q,k] * fv[bh,k,d]
// ---------------------------------------------------------------------------
__global__ __launch_bounds__(256) void pv_kernel(
    const float* __restrict__ fr, const float* __restrict__ fv,
    float* __restrict__ x1)
{
    __shared__ __align__(16) float Ps[64][68];
    __shared__ __align__(16) float Vs[64][68];
    const int bh = blockIdx.y;
    const int b = bh >> 3, h = bh & 7;
    const int q0 = blockIdx.x * 64;
    const int t = threadIdx.x;
    const int tq = t >> 4, tn = t & 15;
    float acc[4][4] = {};
    for (int k0 = 0; k0 < T_; k0 += 64) {
        #pragma unroll
        for (int i = 0; i < 16; ++i) {
            int idx = t + i*256;
            int r = idx >> 6, c = idx & 63;
            int q = q0 + r;
            Ps[r][c] = (q < T_ && (k0 + c) < T_)
                       ? fr[((size_t)bh*T_ + q)*T_ + k0 + c] : 0.f;
            int kr = k0 + r;
            Vs[r][c] = (kr < T_) ? fv[((size_t)bh*T_ + kr)*64 + c] : 0.f;
        }
        __syncthreads();
        #pragma unroll
        for (int kk0 = 0; kk0 < 64; kk0 += 4) {
            float4 a4[4];
            #pragma unroll
            for (int i = 0; i < 4; ++i) a4[i] = *(const float4*)&Ps[tq*4+i][kk0];
            float bb[4][4];
            #pragma unroll
            for (int kkk = 0; kkk < 4; ++kkk) {
                float4 v4 = *(const float4*)&Vs[kk0+kkk][tn*4];
                bb[kkk][0]=v4.x; bb[kkk][1]=v4.y; bb[kkk][2]=v4.z; bb[kkk][3]=v4.w;
            }
            #pragma unroll
            for (int i = 0; i < 4; ++i)
                #pragma unroll
                for (int j = 0; j < 4; ++j)
                    acc[i][j] += a4[i].x*bb[0][j] + a4[i].y*bb[1][j]
                               + a4[i].z*bb[2][j] + a4[i].w*bb[3][j];
        }
        __syncthreads();
    }
    #pragma unroll
    for (int i = 0; i < 4; ++i) {
        int q = q0 + tq*4 + i;
        if (q >= T_) continue;
        #pragma unroll
        for (int j = 0; j < 4; ++j) {
            int dd = tn*4 + j;
            x1[(((size_t)b*T_ + q)*512) + h*64 + dd] = acc[i][j];
        }
    }
}

// ---------------------------------------------------------------------------
extern "C" void kernel_launch(void* const* d_in, const int* in_sizes, int n_in,
                              void* d_out, int out_size, void* d_ws, size_t ws_size,
                              hipStream_t stream)
{
    (void)in_sizes; (void)n_in; (void)out_size; (void)ws_size;
    const float* x_head   = (const float*)d_in[0];
    const float* x_tail   = (const float*)d_in[1];
    const int*   ids      = (const int*)  d_in[2];
    const float* W_head_w = (const float*)d_in[3];
    const float* W_head_b = (const float*)d_in[4];
    const float* W_v_w    = (const float*)d_in[5];
    const float* W_v_b    = (const float*)d_in[6];
    const float* W_out_w  = (const float*)d_in[7];
    const float* W_out_b  = (const float*)d_in[8];
    const float* rel      = (const float*)d_in[9];
    const float* col_h    = (const float*)d_in[10];
    const float* col_t    = (const float*)d_in[11];
    const float* biasp    = (const float*)d_in[12];

    float* ws = (float*)d_ws;
    const size_t F = (size_t)BH_*T_*64;     // 3,149,824 floats
    const size_t C = (size_t)BH_*T_*DCOL_;  // 1,082,752 floats
    float* fh  = ws;
    float* ft  = fh + F;
    float* fv  = ft + F;
    float* chg = fv + F;
    float* ctg = chg + C;
    float* x1  = fh;          // fh is dead after score_kernel; reuse for x1
    float* xout = (float*)d_out;
    float* fr   = xout + (size_t)BT_*D_;

    dim3 blk(256, 1, 1);
    dim3 gProj(8, 97, 1);   // N-tiles x M-tiles
    gemm_proj<<<gProj, blk, 0, stream>>>(x_head, W_head_w, W_head_b, rel, fh, 0);
    gemm_proj<<<gProj, blk, 0, stream>>>(x_tail, W_head_w, W_head_b, rel, ft, 1);
    gemm_proj<<<gProj, blk, 0, stream>>>(x_tail, W_v_w,    W_v_b,    rel, fv, 1);

    int gatherThreads = 2 * BH_ * T_;
    gather_norm<<<(gatherThreads + 255)/256, blk, 0, stream>>>(col_h, col_t, ids, chg, ctg);

    dim3 gScore(13, 13, 64);   // k-tiles x q-tiles x (b*h)
    score_kernel<<<gScore, blk, 0, stream>>>(fh, ft, chg, ctg, biasp, fr);

    softmax_kernel<<<BH_*T_, blk, 0, stream>>>(fr);

    dim3 gPV(13, 64, 1);       // q-tiles x (b*h)
    pv_kernel<<<gPV, blk, 0, stream>>>(fr, fv, x1);

    gemm_proj<<<gProj, blk, 0, stream>>>(x1, W_out_w, W_out_b, rel, xout, 3);
}

// Round 2
// 932.323 us; speedup vs baseline: 4.5271x; 4.5271x over previous
//
#include <hip/hip_runtime.h>

#define D_     512
#define H_     8
#define DH_    64
#define NCOLS_ 2048
#define DCOL_  22
#define B_     8
#define NKEEP_ 768
#define T_     769
#define BT_    (B_*T_)   // 6152
#define BH_    (B_*H_)   // 64

// ---------------------------------------------------------------------------
// GEMM: C = A[M,512] @ W[512,512]^T + bias
// mode 0: out[b,h,t,dh] = (v+bias)*rel[n]*0.125   (head proj; fold rel & 1/sqrt(dh))
// mode 1: out[b,h,t,dh] = v+bias                  (tail / value proj)
// mode 3: out[m*512+n]  = v+bias                  (output proj, plain layout)
// ---------------------------------------------------------------------------
__global__ __launch_bounds__(256) void gemm_proj(
    const float* __restrict__ A, const float* __restrict__ W,
    const float* __restrict__ bias, const float* __restrict__ rel,
    float* __restrict__ out, const int mode)
{
    __shared__ __align__(16) float As[16][68];
    __shared__ __align__(16) float Bs[16][68];
    const int t  = threadIdx.x;
    const int m0 = blockIdx.y * 64;
    const int n0 = blockIdx.x * 64;
    const int tm = t >> 4, tn = t & 15;
    float acc[4][4] = {};
    for (int k0 = 0; k0 < 512; k0 += 16) {
        #pragma unroll
        for (int i = 0; i < 4; ++i) {
            int idx = t + i*256;
            int mm = idx >> 4;
            int kk = idx & 15;
            int row = m0 + mm;
            As[kk][mm] = (row < BT_) ? A[(size_t)row*512 + k0 + kk] : 0.f;
            Bs[kk][mm] = W[(size_t)(n0 + mm)*512 + k0 + kk];
        }
        __syncthreads();
        #pragma unroll
        for (int kk = 0; kk < 16; ++kk) {
            float4 a4 = *(const float4*)&As[kk][tm*4];
            float4 b4 = *(const float4*)&Bs[kk][tn*4];
            float av[4] = {a4.x, a4.y, a4.z, a4.w};
            float bv[4] = {b4.x, b4.y, b4.z, b4.w};
            #pragma unroll
            for (int i = 0; i < 4; ++i)
                #pragma unroll
                for (int j = 0; j < 4; ++j)
                    acc[i][j] += av[i] * bv[j];
        }
        __syncthreads();
    }
    #pragma unroll
    for (int i = 0; i < 4; ++i) {
        int m = m0 + tm*4 + i;
        if (m >= BT_) continue;
        int b = m / T_, tt = m % T_;
        #pragma unroll
        for (int j = 0; j < 4; ++j) {
            int n = n0 + tn*4 + j;
            float v = acc[i][j] + bias[n];
            if (mode == 3) {
                out[(size_t)m*512 + n] = v;
            } else {
                if (mode == 0) v *= rel[n] * 0.125f;
                int h = n >> 6, dh = n & 63;
                out[(((size_t)b*H_ + h)*T_ + tt)*64 + dh] = v;
            }
        }
    }
}

// ---------------------------------------------------------------------------
// Normalize col_head/col_tail rows and gather per ids_keep.
// ---------------------------------------------------------------------------
__global__ void gather_norm(
    const float* __restrict__ col_head, const float* __restrict__ col_tail,
    const int* __restrict__ ids, float* __restrict__ chg, float* __restrict__ ctg)
{
    int r = blockIdx.x * blockDim.x + threadIdx.x;
    const int total = BH_ * T_;
    if (r >= 2*total) return;
    const bool tail = (r >= total);
    int rr = tail ? r - total : r;
    int bh = rr / T_;
    int q  = rr - bh*T_;
    int b  = bh >> 3, h = bh & 7;
    int src = (q == 0) ? 0 : (1 + ids[b*NKEEP_ + q - 1]);
    const float* cp = (tail ? col_tail : col_head) + ((size_t)h*NCOLS_ + src)*DCOL_;
    float v[DCOL_];
    float ss = 0.f;
    #pragma unroll
    for (int j = 0; j < DCOL_; ++j) { v[j] = cp[j]; ss += v[j]*v[j]; }
    float inv = 1.0f / sqrtf(ss);
    float* op = (tail ? ctg : chg) + (size_t)rr*DCOL_;
    #pragma unroll
    for (int j = 0; j < DCOL_; ++j) op[j] = v[j]*inv;
}

// ---------------------------------------------------------------------------
// Score: S[q,k] = dot64(fh',ft) + ((top22+bias>0 && q!=k && k!=0) ? 0 : -1e4)
// Two phases sharing one LDS buffer pair (K-major staging, gemm_proj style):
//   Phase 1: 22-dim gate matmul -> 16-bit keep mask (acc reused)
//   Phase 2: 64-dim weight matmul -> acc
// Per k-step only 2 float4 LDS reads (vs 8 in round 1) -> no spill.
// ---------------------------------------------------------------------------
__global__ __launch_bounds__(256) void score_kernel(
    const float* __restrict__ fh, const float* __restrict__ ft,
    const float* __restrict__ chg, const float* __restrict__ ctg,
    const float* __restrict__ biasp, float* __restrict__ fr)
{
    __shared__ __align__(16) float Sa[64][68];   // [d][row], K-major
    __shared__ __align__(16) float Sb[64][68];
    const int bh = blockIdx.z;
    const int q0 = blockIdx.y * 64;
    const int k0 = blockIdx.x * 64;
    const int t  = threadIdx.x;
    const int tq = t >> 4, tk = t & 15;

    float acc[4][4] = {};

    // ---- Phase 1: gate (22-dim dot of normalized col embeddings) ----
    for (int idx = t; idx < 64*24; idx += 256) {
        int r = idx / 24, c = idx - r*24;      // r = tile row, c = col-dim
        int q = q0 + r, k = k0 + r;
        Sa[c][r] = (c < DCOL_ && q < T_) ? chg[((size_t)bh*T_ + q)*DCOL_ + c] : 0.f;
        Sb[c][r] = (c < DCOL_ && k < T_) ? ctg[((size_t)bh*T_ + k)*DCOL_ + c] : 0.f;
    }
    __syncthreads();
    #pragma unroll 2
    for (int d = 0; d < DCOL_; ++d) {
        float4 a4 = *(const float4*)&Sa[d][tq*4];
        float4 b4 = *(const float4*)&Sb[d][tk*4];
        float av[4] = {a4.x, a4.y, a4.z, a4.w};
        float bv[4] = {b4.x, b4.y, b4.z, b4.w};
        #pragma unroll
        for (int i = 0; i < 4; ++i)
            #pragma unroll
            for (int j = 0; j < 4; ++j)
                acc[i][j] += av[i] * bv[j];
    }
    const float bias = biasp[0];
    int keep_bits = 0;
    #pragma unroll
    for (int i = 0; i < 4; ++i)
        #pragma unroll
        for (int j = 0; j < 4; ++j) {
            if (acc[i][j] + bias > 0.f) keep_bits |= 1 << (i*4 + j);
            acc[i][j] = 0.f;
        }
    __syncthreads();

    // ---- Phase 2: weight score (64-dim) ----
    #pragma unroll 4
    for (int i = 0; i < 16; ++i) {
        int idx = t + i*256;
        int r = idx >> 6, c = idx & 63;        // r = tile row, c = head-dim
        int q = q0 + r, k = k0 + r;
        Sa[c][r] = (q < T_) ? fh[((size_t)bh*T_ + q)*64 + c] : 0.f;
        Sb[c][r] = (k < T_) ? ft[((size_t)bh*T_ + k)*64 + c] : 0.f;
    }
    __syncthreads();
    #pragma unroll 4
    for (int d = 0; d < 64; ++d) {
        float4 a4 = *(const float4*)&Sa[d][tq*4];
        float4 b4 = *(const float4*)&Sb[d][tk*4];
        float av[4] = {a4.x, a4.y, a4.z, a4.w};
        float bv[4] = {b4.x, b4.y, b4.z, b4.w};
        #pragma unroll
        for (int i = 0; i < 4; ++i)
            #pragma unroll
            for (int j = 0; j < 4; ++j)
                acc[i][j] += av[i] * bv[j];
    }

    #pragma unroll
    for (int i = 0; i < 4; ++i) {
        int q = q0 + tq*4 + i;
        if (q >= T_) continue;
        #pragma unroll
        for (int j = 0; j < 4; ++j) {
            int k = k0 + tk*4 + j;
            if (k >= T_) continue;
            bool keep = ((keep_bits >> (i*4 + j)) & 1) && (q != k) && (k != 0);
            fr[((size_t)bh*T_ + q)*T_ + k] = acc[i][j] + (keep ? 0.f : -10000.f);
        }
    }
}

// ---------------------------------------------------------------------------
// Row softmax in-place on fr (one block per row, 769 elements).
// ---------------------------------------------------------------------------
__global__ __launch_bounds__(256) void softmax_kernel(float* __restrict__ fr)
{
    __shared__ float red[4];
    const int t = threadIdx.x;
    float* p = fr + (size_t)blockIdx.x * T_;
    float v[4];
    float m = -3.4e38f;
    #pragma unroll
    for (int i = 0; i < 4; ++i) {
        int idx = t + i*256;
        v[i] = (idx < T_) ? p[idx] : -3.4e38f;
        m = fmaxf(m, v[i]);
    }
    #pragma unroll
    for (int off = 32; off > 0; off >>= 1) m = fmaxf(m, __shfl_xor(m, off, 64));
    if ((t & 63) == 0) red[t >> 6] = m;
    __syncthreads();
    m = fmaxf(fmaxf(red[0], red[1]), fmaxf(red[2], red[3]));
    __syncthreads();
    float e[4]; float s = 0.f;
    #pragma unroll
    for (int i = 0; i < 4; ++i) {
        int idx = t + i*256;
        e[i] = (idx < T_) ? expf(v[i] - m) : 0.f;
        s += e[i];
    }
    #pragma unroll
    for (int off = 32; off > 0; off >>= 1) s += __shfl_xor(s, off, 64);
    if ((t & 63) == 0) red[t >> 6] = s;
    __syncthreads();
    s = red[0] + red[1] + red[2] + red[3];
    float inv = 1.0f / s;
    #pragma unroll
    for (int i = 0; i < 4; ++i) {
        int idx = t + i*256;
        if (idx < T_) p[idx] = e[i] * inv;
    }
}

// ---------------------------------------------------------------------------
// PV: x1[b,q,h*64+d] = sum_k fr[bh,q,k] * fv[bh,k,d]
// ---------------------------------------------------------------------------
__global__ __launch_bounds__(256) void pv_kernel(
    const float* __restrict__ fr, const float* __restrict__ fv,
    float* __restrict__ x1)
{
    __shared__ __align__(16) float Ps[64][68];
    __shared__ __align__(16) float Vs[64][68];
    const int bh = blockIdx.y;
    const int b = bh >> 3, h = bh & 7;
    const int q0 = blockIdx.x * 64;
    const int t = threadIdx.x;
    const int tq = t >> 4, tn = t & 15;
    float acc[4][4] = {};
    for (int k0 = 0; k0 < T_; k0 += 64) {
        #pragma unroll 4
        for (int i = 0; i < 16; ++i) {
            int idx = t + i*256;
            int r = idx >> 6, c = idx & 63;
            int q = q0 + r;
            // Ps staged K-major: Ps[k][q]
            Ps[c][r] = (q < T_ && (k0 + c) < T_)
                       ? fr[((size_t)bh*T_ + q)*T_ + k0 + c] : 0.f;
            int kr = k0 + r;
            Vs[r][c] = (kr < T_) ? fv[((size_t)bh*T_ + kr)*64 + c] : 0.f;
        }
        __syncthreads();
        #pragma unroll 4
        for (int kk = 0; kk < 64; ++kk) {
            float4 a4 = *(const float4*)&Ps[kk][tq*4];
            float4 b4 = *(const float4*)&Vs[kk][tn*4];
            float av[4] = {a4.x, a4.y, a4.z, a4.w};
            float bv[4] = {b4.x, b4.y, b4.z, b4.w};
            #pragma unroll
            for (int i = 0; i < 4; ++i)
                #pragma unroll
                for (int j = 0; j < 4; ++j)
                    acc[i][j] += av[i] * bv[j];
        }
        __syncthreads();
    }
    #pragma unroll
    for (int i = 0; i < 4; ++i) {
        int q = q0 + tq*4 + i;
        if (q >= T_) continue;
        #pragma unroll
        for (int j = 0; j < 4; ++j) {
            int dd = tn*4 + j;
            x1[(((size_t)b*T_ + q)*512) + h*64 + dd] = acc[i][j];
        }
    }
}

// ---------------------------------------------------------------------------
extern "C" void kernel_launch(void* const* d_in, const int* in_sizes, int n_in,
                              void* d_out, int out_size, void* d_ws, size_t ws_size,
                              hipStream_t stream)
{
    (void)in_sizes; (void)n_in; (void)out_size; (void)ws_size;
    const float* x_head   = (const float*)d_in[0];
    const float* x_tail   = (const float*)d_in[1];
    const int*   ids      = (const int*)  d_in[2];
    const float* W_head_w = (const float*)d_in[3];
    const float* W_head_b = (const float*)d_in[4];
    const float* W_v_w    = (const float*)d_in[5];
    const float* W_v_b    = (const float*)d_in[6];
    const float* W_out_w  = (const float*)d_in[7];
    const float* W_out_b  = (const float*)d_in[8];
    const float* rel      = (const float*)d_in[9];
    const float* col_h    = (const float*)d_in[10];
    const float* col_t    = (const float*)d_in[11];
    const float* biasp    = (const float*)d_in[12];

    float* ws = (float*)d_ws;
    const size_t F = (size_t)BH_*T_*64;     // 3,149,824 floats
    const size_t C = (size_t)BH_*T_*DCOL_;  // 1,082,752 floats
    float* fh  = ws;
    float* ft  = fh + F;
    float* fv  = ft + F;
    float* chg = fv + F;
    float* ctg = chg + C;
    float* x1  = fh;          // fh is dead after score_kernel; reuse for x1
    float* xout = (float*)d_out;
    float* fr   = xout + (size_t)BT_*D_;

    dim3 blk(256, 1, 1);
    dim3 gProj(8, 97, 1);   // N-tiles x M-tiles
    gemm_proj<<<gProj, blk, 0, stream>>>(x_head, W_head_w, W_head_b, rel, fh, 0);
    gemm_proj<<<gProj, blk, 0, stream>>>(x_tail, W_head_w, W_head_b, rel, ft, 1);
    gemm_proj<<<gProj, blk, 0, stream>>>(x_tail, W_v_w,    W_v_b,    rel, fv, 1);

    int gatherThreads = 2 * BH_ * T_;
    gather_norm<<<(gatherThreads + 255)/256, blk, 0, stream>>>(col_h, col_t, ids, chg, ctg);

    dim3 gScore(13, 13, 64);   // k-tiles x q-tiles x (b*h)
    score_kernel<<<gScore, blk, 0, stream>>>(fh, ft, chg, ctg, biasp, fr);

    softmax_kernel<<<BH_*T_, blk, 0, stream>>>(fr);

    dim3 gPV(13, 64, 1);       // q-tiles x (b*h)
    pv_kernel<<<gPV, blk, 0, stream>>>(fr, fv, x1);

    gemm_proj<<<gProj, blk, 0, stream>>>(x1, W_out_w, W_out_b, rel, xout, 3);
}

// Round 3
// 479.320 us; speedup vs baseline: 8.8056x; 1.9451x over previous
//
#include <hip/hip_runtime.h>

#define D_     512
#define H_     8
#define NCOLS_ 2048
#define DCOL_  22
#define B_     8
#define NKEEP_ 768
#define T_     769
#define BT_    (B_*T_)   // 6152
#define BH_    (B_*H_)   // 64

typedef __attribute__((ext_vector_type(8))) short bf16x8;
typedef __attribute__((ext_vector_type(4))) float f32x4;

__device__ __forceinline__ ushort f2bf(float f) {
    unsigned u = __float_as_uint(f);
    unsigned r = u + 0x7fffu + ((u >> 16) & 1u);   // RNE
    return (ushort)(r >> 16);
}

// ---------------------------------------------------------------------------
// fp32 -> bf16 cast (vec4)
// ---------------------------------------------------------------------------
__global__ __launch_bounds__(256) void cast_bf16(
    const float* __restrict__ src, ushort* __restrict__ dst, int n4)
{
    int i = blockIdx.x * 256 + threadIdx.x;
    if (i >= n4) return;
    float4 v = ((const float4*)src)[i];
    ushort4 o;
    o.x = f2bf(v.x); o.y = f2bf(v.y); o.z = f2bf(v.z); o.w = f2bf(v.w);
    ((ushort4*)dst)[i] = o;
}

// ---------------------------------------------------------------------------
// bf16 MFMA GEMM: C[M,512] = A[M,512] @ W[512,512]^T + bias
// 128x128 tile, 4 waves (64x64 quadrant each, 4x4 frags of 16x16x32), BK=32.
// mode 0: bf16 out, head-split, *rel*0.125
// mode 1: bf16 out, head-split
// mode 3: fp32 out, plain [m*512+n]
// ---------------------------------------------------------------------------
__global__ __launch_bounds__(256) void gemm_mfma(
    const ushort* __restrict__ A, const ushort* __restrict__ W,
    const float* __restrict__ bias, const float* __restrict__ rel,
    ushort* __restrict__ outb, float* __restrict__ outf,
    const int M, const int mode)
{
    __shared__ __align__(16) ushort As[128*40];
    __shared__ __align__(16) ushort Bs[128*40];
    const int t    = threadIdx.x;
    const int lane = t & 63;
    const int wv   = t >> 6;
    const int wr   = wv >> 1, wc = wv & 1;
    const int m16  = lane & 15, q4 = lane >> 4;
    const int m0   = blockIdx.y * 128;
    const int n0   = blockIdx.x * 128;
    const int sr   = t >> 1;            // staging row 0..127
    const int sh   = t & 1;             // staging half (16 elems)

    f32x4 acc[4][4] = {};
    for (int k0 = 0; k0 < 512; k0 += 32) {
        // stage A,B tiles (128 x 32 bf16 each)
        {
            int row = m0 + sr;
            bf16x8 z = {};
            bf16x8 v0 = z, v1 = z;
            if (row < M) {
                const bf16x8* gp = (const bf16x8*)(A + (size_t)row*512 + k0 + sh*16);
                v0 = gp[0]; v1 = gp[1];
            }
            *(bf16x8*)&As[sr*40 + sh*16]     = v0;
            *(bf16x8*)&As[sr*40 + sh*16 + 8] = v1;
            const bf16x8* wp = (const bf16x8*)(W + (size_t)(n0 + sr)*512 + k0 + sh*16);
            *(bf16x8*)&Bs[sr*40 + sh*16]     = wp[0];
            *(bf16x8*)&Bs[sr*40 + sh*16 + 8] = wp[1];
        }
        __syncthreads();
        bf16x8 a[4], b[4];
        #pragma unroll
        for (int i = 0; i < 4; ++i)
            a[i] = *(const bf16x8*)&As[(wr*64 + i*16 + m16)*40 + q4*8];
        #pragma unroll
        for (int j = 0; j < 4; ++j)
            b[j] = *(const bf16x8*)&Bs[(wc*64 + j*16 + m16)*40 + q4*8];
        #pragma unroll
        for (int i = 0; i < 4; ++i)
            #pragma unroll
            for (int j = 0; j < 4; ++j)
                acc[i][j] = __builtin_amdgcn_mfma_f32_16x16x32_bf16(a[i], b[j], acc[i][j], 0, 0, 0);
        __syncthreads();
    }

    // epilogue
    #pragma unroll
    for (int j = 0; j < 4; ++j) {
        const int n = n0 + wc*64 + j*16 + m16;
        const float bn = bias[n];
        const float sc = (mode == 0) ? rel[n] * 0.125f : 1.0f;
        const int h = n >> 6, dh = n & 63;
        #pragma unroll
        for (int i = 0; i < 4; ++i) {
            #pragma unroll
            for (int r = 0; r < 4; ++r) {
                int m = m0 + wr*64 + i*16 + q4*4 + r;
                if (m >= M) continue;
                float v = acc[i][j][r] + bn;
                if (mode == 3) {
                    outf[(size_t)m*512 + n] = v;
                } else {
                    if (mode == 0) v *= sc;
                    int bb = m / T_, tt = m - bb*T_;
                    outb[(((size_t)bb*H_ + h)*T_ + tt)*64 + dh] = f2bf(v);
                }
            }
        }
    }
}

// ---------------------------------------------------------------------------
// Normalize col_head/col_tail rows and gather per ids_keep (fp32, exact).
// ---------------------------------------------------------------------------
__global__ void gather_norm(
    const float* __restrict__ col_head, const float* __restrict__ col_tail,
    const int* __restrict__ ids, float* __restrict__ chg, float* __restrict__ ctg)
{
    int r = blockIdx.x * blockDim.x + threadIdx.x;
    const int total = BH_ * T_;
    if (r >= 2*total) return;
    const bool tail = (r >= total);
    int rr = tail ? r - total : r;
    int bh = rr / T_;
    int q  = rr - bh*T_;
    int b  = bh >> 3, h = bh & 7;
    int src = (q == 0) ? 0 : (1 + ids[b*NKEEP_ + q - 1]);
    const float* cp = (tail ? col_tail : col_head) + ((size_t)h*NCOLS_ + src)*DCOL_;
    float v[DCOL_];
    float ss = 0.f;
    #pragma unroll
    for (int j = 0; j < DCOL_; ++j) { v[j] = cp[j]; ss += v[j]*v[j]; }
    float inv = 1.0f / sqrtf(ss);
    float* op = (tail ? ctg : chg) + (size_t)rr*DCOL_;
    #pragma unroll
    for (int j = 0; j < DCOL_; ++j) op[j] = v[j]*inv;
}

// ---------------------------------------------------------------------------
// Score: 128x128 tile of S per (bh).  Gate fp32 (exact sign test) computed in
// the MFMA C-fragment pattern; weight score via bf16 MFMA; writes fr fp32.
// ---------------------------------------------------------------------------
__global__ __launch_bounds__(256) void score_mfma(
    const ushort* __restrict__ fhb, const ushort* __restrict__ ftb,
    const float* __restrict__ chg, const float* __restrict__ ctg,
    const float* __restrict__ biasp, float* __restrict__ fr)
{
    __shared__ __align__(16) char smem[128*72*2*2];   // 36,864 B, reused
    float*  Gq = (float*)smem;            // [22][132]
    float*  Gk = Gq + 22*132;
    ushort* Qs = (ushort*)smem;           // [128][72]
    ushort* Ks = Qs + 128*72;

    const int bh = blockIdx.z;
    const int q0 = blockIdx.y * 128;
    const int k0 = blockIdx.x * 128;
    const int t    = threadIdx.x;
    const int lane = t & 63;
    const int wv   = t >> 6;
    const int wr   = wv >> 1, wc = wv & 1;
    const int m16  = lane & 15, q4 = lane >> 4;

    // ---- stage gate operands (transposed: [d][row]) ----
    {
        if (t < 128) {
            int q = q0 + t;
            const float* p = chg + ((size_t)bh*T_ + q)*DCOL_;
            #pragma unroll 2
            for (int d = 0; d < DCOL_; ++d)
                Gq[d*132 + t] = (q < T_) ? p[d] : 0.f;
        } else {
            int r = t - 128;
            int k = k0 + r;
            const float* p = ctg + ((size_t)bh*T_ + k)*DCOL_;
            #pragma unroll 2
            for (int d = 0; d < DCOL_; ++d)
                Gk[d*132 + r] = (k < T_) ? p[d] : 0.f;
        }
    }
    __syncthreads();

    // ---- gate compute, fp32, in C-fragment pattern ----
    unsigned long long km = 0ull;
    {
        float ga[4][4][4] = {};
        #pragma unroll 2
        for (int d = 0; d < DCOL_; ++d) {
            float4 aq[4];
            float  bk[4];
            #pragma unroll
            for (int i = 0; i < 4; ++i)
                aq[i] = *(const float4*)&Gq[d*132 + wr*64 + i*16 + q4*4];
            #pragma unroll
            for (int j = 0; j < 4; ++j)
                bk[j] = Gk[d*132 + wc*64 + j*16 + m16];
            #pragma unroll
            for (int i = 0; i < 4; ++i) {
                float av[4] = {aq[i].x, aq[i].y, aq[i].z, aq[i].w};
                #pragma unroll
                for (int r = 0; r < 4; ++r)
                    #pragma unroll
                    for (int j = 0; j < 4; ++j)
                        ga[i][r][j] += av[r] * bk[j];
            }
        }
        const float bias0 = biasp[0];
        #pragma unroll
        for (int i = 0; i < 4; ++i)
            #pragma unroll
            for (int r = 0; r < 4; ++r)
                #pragma unroll
                for (int j = 0; j < 4; ++j)
                    if (ga[i][r][j] + bias0 > 0.f)
                        km |= 1ull << (i*16 + r*4 + j);
    }
    __syncthreads();

    // ---- stage Q/K tiles (128 x 64 bf16, stride 72) ----
    {
        const int sr = t >> 1, sh = t & 1;   // row, 32-elem half
        int q = q0 + sr, k = k0 + sr;
        bf16x8 z = {};
        const bf16x8* qp = (const bf16x8*)(fhb + ((size_t)bh*T_ + q)*64 + sh*32);
        const bf16x8* kp = (const bf16x8*)(ftb + ((size_t)bh*T_ + k)*64 + sh*32);
        #pragma unroll
        for (int e = 0; e < 4; ++e) {
            *(bf16x8*)&Qs[sr*72 + sh*32 + e*8] = (q < T_) ? qp[e] : z;
            *(bf16x8*)&Ks[sr*72 + sh*32 + e*8] = (k < T_) ? kp[e] : z;
        }
    }
    __syncthreads();

    // ---- MFMA weight score ----
    f32x4 acc[4][4] = {};
    #pragma unroll
    for (int c = 0; c < 2; ++c) {
        bf16x8 a[4], b[4];
        #pragma unroll
        for (int i = 0; i < 4; ++i)
            a[i] = *(const bf16x8*)&Qs[(wr*64 + i*16 + m16)*72 + c*32 + q4*8];
        #pragma unroll
        for (int j = 0; j < 4; ++j)
            b[j] = *(const bf16x8*)&Ks[(wc*64 + j*16 + m16)*72 + c*32 + q4*8];
        #pragma unroll
        for (int i = 0; i < 4; ++i)
            #pragma unroll
            for (int j = 0; j < 4; ++j)
                acc[i][j] = __builtin_amdgcn_mfma_f32_16x16x32_bf16(a[i], b[j], acc[i][j], 0, 0, 0);
    }

    // ---- mask + store ----
    #pragma unroll
    for (int i = 0; i < 4; ++i) {
        #pragma unroll
        for (int j = 0; j < 4; ++j) {
            const int k = k0 + wc*64 + j*16 + m16;
            #pragma unroll
            for (int r = 0; r < 4; ++r) {
                int q = q0 + wr*64 + i*16 + q4*4 + r;
                if (q >= T_ || k >= T_) continue;
                bool kp = ((km >> (i*16 + r*4 + j)) & 1ull) && (q != k) && (k != 0);
                fr[((size_t)bh*T_ + q)*T_ + k] = acc[i][j][r] + (kp ? 0.f : -10000.f);
            }
        }
    }
}

// ---------------------------------------------------------------------------
// Row softmax in-place on fr (one block per row, 769 elements).
// ---------------------------------------------------------------------------
__global__ __launch_bounds__(256) void softmax_kernel(float* __restrict__ fr)
{
    __shared__ float red[4];
    const int t = threadIdx.x;
    float* p = fr + (size_t)blockIdx.x * T_;
    float v[4];
    float m = -3.4e38f;
    #pragma unroll
    for (int i = 0; i < 4; ++i) {
        int idx = t + i*256;
        v[i] = (idx < T_) ? p[idx] : -3.4e38f;
        m = fmaxf(m, v[i]);
    }
    #pragma unroll
    for (int off = 32; off > 0; off >>= 1) m = fmaxf(m, __shfl_xor(m, off, 64));
    if ((t & 63) == 0) red[t >> 6] = m;
    __syncthreads();
    m = fmaxf(fmaxf(red[0], red[1]), fmaxf(red[2], red[3]));
    __syncthreads();
    float e[4]; float s = 0.f;
    #pragma unroll
    for (int i = 0; i < 4; ++i) {
        int idx = t + i*256;
        e[i] = (idx < T_) ? expf(v[i] - m) : 0.f;
        s += e[i];
    }
    #pragma unroll
    for (int off = 32; off > 0; off >>= 1) s += __shfl_xor(s, off, 64);
    if ((t & 63) == 0) red[t >> 6] = s;
    __syncthreads();
    s = red[0] + red[1] + red[2] + red[3];
    float inv = 1.0f / s;
    #pragma unroll
    for (int i = 0; i < 4; ++i) {
        int idx = t + i*256;
        if (idx < T_) p[idx] = e[i] * inv;
    }
}

// ---------------------------------------------------------------------------
// PV via MFMA: x1[b,q,h*64+d] = sum_k fr[bh,q,k] * fv[bh,k,d], bf16 out.
// 128q x 64d tile per block, k-loop BK=32.  P cast fp32->bf16 in staging;
// V staged transposed [d][k] (stride 40) for B-operand frag reads.
// ---------------------------------------------------------------------------
__global__ __launch_bounds__(256) void pv_mfma(
    const float* __restrict__ fr, const ushort* __restrict__ fvb,
    ushort* __restrict__ x1b)
{
    __shared__ __align__(16) ushort Ps[128*40];
    __shared__ __align__(16) ushort Vs[64*40];
    const int bh = blockIdx.y;
    const int b = bh >> 3, h = bh & 7;
    const int q0 = blockIdx.x * 128;
    const int t    = threadIdx.x;
    const int lane = t & 63;
    const int wv   = t >> 6;
    const int m16  = lane & 15, q4 = lane >> 4;

    f32x4 acc[2][4] = {};
    for (int kk0 = 0; kk0 < 800; kk0 += 32) {
        // stage P: rows q0..q0+127, k kk0..kk0+31, fp32 -> bf16
        {
            const int sr = t >> 1, sh = t & 1;
            int q = q0 + sr;
            const float* p = fr + ((size_t)bh*T_ + ((q < T_) ? q : 0))*T_ + kk0 + sh*16;
            ushort tmp[16];
            if (q < T_ && kk0 + sh*16 + 15 < T_) {
                #pragma unroll
                for (int e = 0; e < 4; ++e) {
                    float4 v = *(const float4*)(p + e*4);
                    tmp[e*4+0] = f2bf(v.x); tmp[e*4+1] = f2bf(v.y);
                    tmp[e*4+2] = f2bf(v.z); tmp[e*4+3] = f2bf(v.w);
                }
            } else {
                #pragma unroll
                for (int e = 0; e < 16; ++e) {
                    int k = kk0 + sh*16 + e;
                    tmp[e] = (q < T_ && k < T_) ? f2bf(p[e]) : (ushort)0;
                }
            }
            *(bf16x8*)&Ps[sr*40 + sh*16]     = *(bf16x8*)&tmp[0];
            *(bf16x8*)&Ps[sr*40 + sh*16 + 8] = *(bf16x8*)&tmp[8];
        }
        // stage V transposed: Vs[d][k], d 0..63, k 0..31
        {
            const int dg = t >> 5;          // 0..7 -> d = dg*8..+8
            const int k  = t & 31;
            int kg = kk0 + k;
            ushort vv[8];
            if (kg < T_) {
                const bf16x8 v = *(const bf16x8*)(fvb + ((size_t)bh*T_ + kg)*64 + dg*8);
                #pragma unroll
                for (int e = 0; e < 8; ++e) vv[e] = ((ushort)(v[e]));
            } else {
                #pragma unroll
                for (int e = 0; e < 8; ++e) vv[e] = 0;
            }
            #pragma unroll
            for (int e = 0; e < 8; ++e)
                Vs[(dg*8 + e)*40 + k] = vv[e];
        }
        __syncthreads();
        bf16x8 a[2], bb[4];
        #pragma unroll
        for (int i = 0; i < 2; ++i)
            a[i] = *(const bf16x8*)&Ps[(wv*32 + i*16 + m16)*40 + q4*8];
        #pragma unroll
        for (int j = 0; j < 4; ++j)
            bb[j] = *(const bf16x8*)&Vs[(j*16 + m16)*40 + q4*8];
        #pragma unroll
        for (int i = 0; i < 2; ++i)
            #pragma unroll
            for (int j = 0; j < 4; ++j)
                acc[i][j] = __builtin_amdgcn_mfma_f32_16x16x32_bf16(a[i], bb[j], acc[i][j], 0, 0, 0);
        __syncthreads();
    }

    #pragma unroll
    for (int i = 0; i < 2; ++i) {
        #pragma unroll
        for (int j = 0; j < 4; ++j) {
            const int d = j*16 + m16;
            #pragma unroll
            for (int r = 0; r < 4; ++r) {
                int q = q0 + wv*32 + i*16 + q4*4 + r;
                if (q >= T_) continue;
                x1b[((size_t)b*T_ + q)*512 + h*64 + d] = f2bf(acc[i][j][r]);
            }
        }
    }
}

// ---------------------------------------------------------------------------
extern "C" void kernel_launch(void* const* d_in, const int* in_sizes, int n_in,
                              void* d_out, int out_size, void* d_ws, size_t ws_size,
                              hipStream_t stream)
{
    (void)in_sizes; (void)n_in; (void)out_size; (void)ws_size;
    const float* x_head   = (const float*)d_in[0];
    const float* x_tail   = (const float*)d_in[1];
    const int*   ids      = (const int*)  d_in[2];
    const float* W_head_w = (const float*)d_in[3];
    const float* W_head_b = (const float*)d_in[4];
    const float* W_v_w    = (const float*)d_in[5];
    const float* W_v_b    = (const float*)d_in[6];
    const float* W_out_w  = (const float*)d_in[7];
    const float* W_out_b  = (const float*)d_in[8];
    const float* rel      = (const float*)d_in[9];
    const float* col_h    = (const float*)d_in[10];
    const float* col_t    = (const float*)d_in[11];
    const float* biasp    = (const float*)d_in[12];

    const size_t F   = (size_t)BH_*T_*64;      // 3,149,824 (== BT_*512)
    const size_t WSZ = 512*512;
    const size_t C22 = (size_t)BH_*T_*DCOL_;

    char* ws = (char*)d_ws;
    ushort* fhb = (ushort*)ws;            ws += F*2;
    ushort* ftb = (ushort*)ws;            ws += F*2;
    ushort* fvb = (ushort*)ws;            ws += F*2;
    ushort* xhb = (ushort*)ws;            ws += F*2;   // reused as x1b
    ushort* xtb = (ushort*)ws;            ws += F*2;
    ushort* whb = (ushort*)ws;            ws += WSZ*2;
    ushort* wvb = (ushort*)ws;            ws += WSZ*2;
    ushort* wob = (ushort*)ws;            ws += WSZ*2;
    float*  chg = (float*)ws;             ws += C22*4;
    float*  ctg = (float*)ws;             ws += C22*4;
    ushort* x1b = xhb;

    float* xout = (float*)d_out;
    float* fr   = xout + (size_t)BT_*D_;

    dim3 blk(256, 1, 1);

    // casts
    cast_bf16<<<(int)((F/4 + 255)/256),   blk, 0, stream>>>(x_head,   xhb, (int)(F/4));
    cast_bf16<<<(int)((F/4 + 255)/256),   blk, 0, stream>>>(x_tail,   xtb, (int)(F/4));
    cast_bf16<<<(int)((WSZ/4 + 255)/256), blk, 0, stream>>>(W_head_w, whb, (int)(WSZ/4));
    cast_bf16<<<(int)((WSZ/4 + 255)/256), blk, 0, stream>>>(W_v_w,    wvb, (int)(WSZ/4));
    cast_bf16<<<(int)((WSZ/4 + 255)/256), blk, 0, stream>>>(W_out_w,  wob, (int)(WSZ/4));

    // projections
    dim3 gProj(4, 49, 1);
    gemm_mfma<<<gProj, blk, 0, stream>>>(xhb, whb, W_head_b, rel, fhb, nullptr, BT_, 0);
    gemm_mfma<<<gProj, blk, 0, stream>>>(xtb, whb, W_head_b, rel, ftb, nullptr, BT_, 1);
    gemm_mfma<<<gProj, blk, 0, stream>>>(xtb, wvb, W_v_b,    rel, fvb, nullptr, BT_, 1);

    // gate operands
    int gatherThreads = 2 * BH_ * T_;
    gather_norm<<<(gatherThreads + 255)/256, blk, 0, stream>>>(col_h, col_t, ids, chg, ctg);

    // scores + mask
    dim3 gScore(7, 7, BH_);
    score_mfma<<<gScore, blk, 0, stream>>>(fhb, ftb, chg, ctg, biasp, fr);

    softmax_kernel<<<BH_*T_, blk, 0, stream>>>(fr);

    dim3 gPV(7, BH_, 1);
    pv_mfma<<<gPV, blk, 0, stream>>>(fr, fvb, x1b);

    gemm_mfma<<<gProj, blk, 0, stream>>>(x1b, wob, W_out_b, rel, nullptr, xout, BT_, 3);
}

// Round 4
// 453.011 us; speedup vs baseline: 9.3170x; 1.0581x over previous
//
#include <hip/hip_runtime.h>

#define D_     512
#define H_     8
#define NCOLS_ 2048
#define DCOL_  22
#define B_     8
#define NKEEP_ 768
#define T_     769
#define BT_    (B_*T_)   // 6152
#define BH_    (B_*H_)   // 64

typedef __attribute__((ext_vector_type(8))) short bf16x8;
typedef __attribute__((ext_vector_type(4))) float f32x4;

__device__ __forceinline__ ushort f2bf(float f) {
    unsigned u = __float_as_uint(f);
    unsigned r = u + 0x7fffu + ((u >> 16) & 1u);   // RNE
    return (ushort)(r >> 16);
}
__device__ __forceinline__ float bf2f(ushort u) {
    return __uint_as_float(((unsigned)u) << 16);
}

// ---------------------------------------------------------------------------
// Projections: C[M,512] = A[M,512] @ W[512,512]^T + bias  (bf16 MFMA)
// fp32 inputs are cast to bf16 during LDS staging (no separate cast kernels).
// job 0: A=x_head, W=Wh -> fhb  (bf16 out, head-split, *rel*0.125)
// job 1: A=x_tail, W=Wh -> ftb  (bf16 out, head-split)
// job 2: A=x_tail, W=Wv -> fvb  (bf16 out, head-split)
// job 3: A=x1b(bf16), W=Wo -> xout (fp32, plain)  [separate launch]
// ---------------------------------------------------------------------------
__global__ __launch_bounds__(256) void proj_mfma(
    const float* __restrict__ xh, const float* __restrict__ xt,
    const ushort* __restrict__ x1b,
    const float* __restrict__ Wh, const float* __restrict__ Wv,
    const float* __restrict__ Wo,
    const float* __restrict__ bh_, const float* __restrict__ bv_,
    const float* __restrict__ bo_, const float* __restrict__ rel,
    ushort* __restrict__ fhb, ushort* __restrict__ ftb,
    ushort* __restrict__ fvb, float* __restrict__ xout, const int jobParam)
{
    __shared__ __align__(16) ushort As[128*40];
    __shared__ __align__(16) ushort Bs[128*40];
    const int job = (jobParam < 0) ? (int)blockIdx.z : jobParam;
    const float* A32 = nullptr; const ushort* A16 = nullptr;
    const float* W; const float* bias;
    ushort* outb = nullptr; float* outf = nullptr; int mode;
    if (job == 0)      { A32 = xh; W = Wh; bias = bh_; outb = fhb; mode = 0; }
    else if (job == 1) { A32 = xt; W = Wh; bias = bh_; outb = ftb; mode = 1; }
    else if (job == 2) { A32 = xt; W = Wv; bias = bv_; outb = fvb; mode = 1; }
    else               { A16 = x1b; W = Wo; bias = bo_; outf = xout; mode = 3; }

    const int t    = threadIdx.x;
    const int lane = t & 63;
    const int wv   = t >> 6;
    const int wr   = wv >> 1, wc = wv & 1;
    const int m16  = lane & 15, q4 = lane >> 4;
    const int m0   = blockIdx.y * 128;
    const int n0   = blockIdx.x * 128;

    f32x4 acc[4][4] = {};
    for (int k0 = 0; k0 < 512; k0 += 32) {
        {
            const int sr = t >> 1, sh = t & 1;
            const int row = m0 + sr;
            ushort ta[16];
            if (A16) {
                bf16x8 z = {}; bf16x8 v0 = z, v1 = z;
                if (row < BT_) {
                    const bf16x8* gp = (const bf16x8*)(A16 + (size_t)row*512 + k0 + sh*16);
                    v0 = gp[0]; v1 = gp[1];
                }
                *(bf16x8*)&ta[0] = v0; *(bf16x8*)&ta[8] = v1;
            } else {
                #pragma unroll
                for (int e = 0; e < 16; ++e) ta[e] = 0;
                if (row < BT_) {
                    const float* ap = A32 + (size_t)row*512 + k0 + sh*16;
                    #pragma unroll
                    for (int e = 0; e < 4; ++e) {
                        float4 f = *(const float4*)(ap + e*4);
                        ta[e*4+0]=f2bf(f.x); ta[e*4+1]=f2bf(f.y);
                        ta[e*4+2]=f2bf(f.z); ta[e*4+3]=f2bf(f.w);
                    }
                }
            }
            *(bf16x8*)&As[sr*40 + sh*16]     = *(bf16x8*)&ta[0];
            *(bf16x8*)&As[sr*40 + sh*16 + 8] = *(bf16x8*)&ta[8];
            const float* wp = W + (size_t)(n0 + sr)*512 + k0 + sh*16;
            ushort tw[16];
            #pragma unroll
            for (int e = 0; e < 4; ++e) {
                float4 f = *(const float4*)(wp + e*4);
                tw[e*4+0]=f2bf(f.x); tw[e*4+1]=f2bf(f.y);
                tw[e*4+2]=f2bf(f.z); tw[e*4+3]=f2bf(f.w);
            }
            *(bf16x8*)&Bs[sr*40 + sh*16]     = *(bf16x8*)&tw[0];
            *(bf16x8*)&Bs[sr*40 + sh*16 + 8] = *(bf16x8*)&tw[8];
        }
        __syncthreads();
        bf16x8 a[4], b[4];
        #pragma unroll
        for (int i = 0; i < 4; ++i)
            a[i] = *(const bf16x8*)&As[(wr*64 + i*16 + m16)*40 + q4*8];
        #pragma unroll
        for (int j = 0; j < 4; ++j)
            b[j] = *(const bf16x8*)&Bs[(wc*64 + j*16 + m16)*40 + q4*8];
        #pragma unroll
        for (int i = 0; i < 4; ++i)
            #pragma unroll
            for (int j = 0; j < 4; ++j)
                acc[i][j] = __builtin_amdgcn_mfma_f32_16x16x32_bf16(a[i], b[j], acc[i][j], 0, 0, 0);
        __syncthreads();
    }

    #pragma unroll
    for (int j = 0; j < 4; ++j) {
        const int n = n0 + wc*64 + j*16 + m16;
        const float bn = bias[n];
        const float sc = (mode == 0) ? rel[n] * 0.125f : 1.0f;
        const int h = n >> 6, dh = n & 63;
        #pragma unroll
        for (int i = 0; i < 4; ++i) {
            #pragma unroll
            for (int r = 0; r < 4; ++r) {
                int m = m0 + wr*64 + i*16 + q4*4 + r;
                if (m >= BT_) continue;
                float v = acc[i][j][r] + bn;
                if (mode == 3) {
                    outf[(size_t)m*512 + n] = v;
                } else {
                    if (mode == 0) v *= sc;
                    int bb = m / T_, tt = m - bb*T_;
                    outb[(((size_t)bb*H_ + h)*T_ + tt)*64 + dh] = f2bf(v);
                }
            }
        }
    }
}

// ---------------------------------------------------------------------------
// Normalize col_head/col_tail rows and gather per ids_keep (fp32, exact).
// ---------------------------------------------------------------------------
__global__ void gather_norm(
    const float* __restrict__ col_head, const float* __restrict__ col_tail,
    const int* __restrict__ ids, float* __restrict__ chg, float* __restrict__ ctg)
{
    int r = blockIdx.x * blockDim.x + threadIdx.x;
    const int total = BH_ * T_;
    if (r >= 2*total) return;
    const bool tail = (r >= total);
    int rr = tail ? r - total : r;
    int bh = rr / T_;
    int q  = rr - bh*T_;
    int b  = bh >> 3, h = bh & 7;
    int src = (q == 0) ? 0 : (1 + ids[b*NKEEP_ + q - 1]);
    const float* cp = (tail ? col_tail : col_head) + ((size_t)h*NCOLS_ + src)*DCOL_;
    float v[DCOL_];
    float ss = 0.f;
    #pragma unroll
    for (int j = 0; j < DCOL_; ++j) { v[j] = cp[j]; ss += v[j]*v[j]; }
    float inv = 1.0f / sqrtf(ss);
    float* op = (tail ? ctg : chg) + (size_t)rr*DCOL_;
    #pragma unroll
    for (int j = 0; j < DCOL_; ++j) op[j] = v[j]*inv;
}

// ---------------------------------------------------------------------------
// Fused score+gate+exp(no-max softmax)+rowsum+PV.
// Block = (q-strip of 64, bh). 13 k-tiles of 64.
// Writes: packed bf16 unnormalized e into fr row slots (prefix of each row),
//         inv row-sums to invA, normalized O (x1) as bf16.
// Gate is exact fp32 VALU (sign test must match fp32 reference).
// ---------------------------------------------------------------------------
__global__ __launch_bounds__(256) void fused_attn(
    const ushort* __restrict__ fhb, const ushort* __restrict__ ftb,
    const ushort* __restrict__ fvb, const float* __restrict__ chg,
    const float* __restrict__ ctg, const float* __restrict__ biasp,
    float* __restrict__ fr, ushort* __restrict__ x1b, float* __restrict__ invA)
{
    __shared__ __align__(16) ushort Qs[64*72];
    __shared__ __align__(16) ushort Ks[64*72];
    __shared__ __align__(16) ushort Vs[64*72];   // transposed [d][k]
    __shared__ __align__(16) ushort Et[64*72];   // e tile [q][k]
    __shared__ __align__(16) float  Gq[DCOL_*68]; // [d][q]
    __shared__ __align__(16) float  Gk[DCOL_*68]; // [d][k]
    __shared__ float sumP[4*64];
    __shared__ float inv_s[64];

    const int bh = blockIdx.y;
    const int q0 = blockIdx.x * 64;
    const int t    = threadIdx.x;
    const int lane = t & 63, w = t >> 6;
    const int m16  = lane & 15, q4 = lane >> 4;
    const float bias0 = biasp[0];

    // stage Q strip (64 x 64 bf16) + Gq (once)
    {
        int qr = t >> 2, qc = min(q0 + qr, T_-1);
        const ushort* qp = fhb + ((size_t)bh*T_ + qc)*64 + (t&3)*16;
        *(bf16x8*)&Qs[qr*72 + (t&3)*16]     = *(const bf16x8*)qp;
        *(bf16x8*)&Qs[qr*72 + (t&3)*16 + 8] = *(const bf16x8*)(qp + 8);
    }
    for (int idx = t; idx < 64*DCOL_; idx += 256) {
        int r = idx / DCOL_, d = idx - r*DCOL_;
        int qc = min(q0 + r, T_-1);
        Gq[d*68 + r] = chg[((size_t)bh*T_ + qc)*DCOL_ + d];
    }

    float psum[4][4] = {};
    f32x4 Oacc[4] = {};

    for (int kt = 0; kt < 13; ++kt) {
        const int k0g = kt*64;
        __syncthreads();
        // stage K, V(transposed), Gk
        {
            int kr = t >> 2, kc = min(k0g + kr, T_-1);
            const ushort* kp = ftb + ((size_t)bh*T_ + kc)*64 + (t&3)*16;
            *(bf16x8*)&Ks[kr*72 + (t&3)*16]     = *(const bf16x8*)kp;
            *(bf16x8*)&Ks[kr*72 + (t&3)*16 + 8] = *(const bf16x8*)(kp + 8);
            const ushort* vp = fvb + ((size_t)bh*T_ + kc)*64 + (t&3)*16;
            bf16x8 v0 = *(const bf16x8*)vp, v1 = *(const bf16x8*)(vp + 8);
            int dbase = (t&3)*16;
            #pragma unroll
            for (int e = 0; e < 8; ++e) Vs[(dbase+e)*72 + kr]   = (ushort)v0[e];
            #pragma unroll
            for (int e = 0; e < 8; ++e) Vs[(dbase+8+e)*72 + kr] = (ushort)v1[e];
        }
        for (int idx = t; idx < 64*DCOL_; idx += 256) {
            int r = idx / DCOL_, d = idx - r*DCOL_;
            int kc = min(k0g + r, T_-1);
            Gk[d*68 + r] = ctg[((size_t)bh*T_ + kc)*DCOL_ + d];
        }
        __syncthreads();

        // gate (fp32, exact) in MFMA C-layout: this lane's key col is fixed
        const int kL = w*16 + m16;
        const int kg = k0g + kL;
        unsigned kmask = 0;
        {
            float ga[4][4] = {};
            #pragma unroll 2
            for (int d = 0; d < DCOL_; ++d) {
                float gk = Gk[d*68 + kL];
                #pragma unroll
                for (int i = 0; i < 4; ++i) {
                    float4 a4 = *(const float4*)&Gq[d*68 + i*16 + q4*4];
                    ga[i][0] += a4.x*gk; ga[i][1] += a4.y*gk;
                    ga[i][2] += a4.z*gk; ga[i][3] += a4.w*gk;
                }
            }
            const bool kok = (kg != 0) && (kg < T_);
            #pragma unroll
            for (int i = 0; i < 4; ++i)
                #pragma unroll
                for (int r = 0; r < 4; ++r) {
                    int qg = q0 + i*16 + q4*4 + r;
                    if (kok && (ga[i][r] + bias0 > 0.f) && (qg != kg))
                        kmask |= 1u << (i*4 + r);
                }
        }

        // QK^T MFMA (S tile: 64q x 16k-slice per wave)
        f32x4 Sacc[4] = {};
        #pragma unroll
        for (int step = 0; step < 2; ++step) {
            bf16x8 b = *(const bf16x8*)&Ks[kL*72 + step*32 + q4*8];
            #pragma unroll
            for (int i = 0; i < 4; ++i) {
                bf16x8 a = *(const bf16x8*)&Qs[(i*16 + m16)*72 + step*32 + q4*8];
                Sacc[i] = __builtin_amdgcn_mfma_f32_16x16x32_bf16(a, b, Sacc[i], 0, 0, 0);
            }
        }

        // e = keep ? exp(s) : 0 ; accumulate rowsums; write Et (bf16)
        #pragma unroll
        for (int i = 0; i < 4; ++i) {
            #pragma unroll
            for (int r = 0; r < 4; ++r) {
                float e = ((kmask >> (i*4 + r)) & 1u) ? __expf(Sacc[i][r]) : 0.f;
                psum[i][r] += e;
                Et[(i*16 + q4*4 + r)*72 + kL] = f2bf(e);
            }
        }
        __syncthreads();

        // PV MFMA: wave w accumulates O rows w*16..+15 over 64 d
        #pragma unroll
        for (int step = 0; step < 2; ++step) {
            bf16x8 a = *(const bf16x8*)&Et[(w*16 + m16)*72 + step*32 + q4*8];
            #pragma unroll
            for (int j = 0; j < 4; ++j) {
                bf16x8 b = *(const bf16x8*)&Vs[(j*16 + m16)*72 + step*32 + q4*8];
                Oacc[j] = __builtin_amdgcn_mfma_f32_16x16x32_bf16(a, b, Oacc[j], 0, 0, 0);
            }
        }

        // copy Et tile -> packed bf16 prefix of fr rows (coalesced u32 stores)
        {
            const int c = t & 15;
            #pragma unroll
            for (int p = 0; p < 4; ++p) {
                int row = p*16 + (t >> 4);
                int qg = q0 + row;
                if (qg >= T_) continue;
                char* rowbase = (char*)(fr + ((size_t)bh*T_ + qg)*T_);
                #pragma unroll
                for (int e = 0; e < 2; ++e) {
                    int dw = c + 16*e;             // dword index in tile row
                    int kk = k0g + dw*2;
                    unsigned u = *(const unsigned*)&Et[row*72 + dw*2];
                    if (kk + 1 < T_)      *(unsigned*)(rowbase + (size_t)kk*2) = u;
                    else if (kk < T_)     *(ushort*)(rowbase + (size_t)kk*2) = (ushort)u;
                }
            }
        }
    }

    // reduce rowsums over the 16 k-columns (m16) per wave
    #pragma unroll
    for (int i = 0; i < 4; ++i)
        #pragma unroll
        for (int r = 0; r < 4; ++r) {
            float v = psum[i][r];
            v += __shfl_xor(v, 1, 64);
            v += __shfl_xor(v, 2, 64);
            v += __shfl_xor(v, 4, 64);
            v += __shfl_xor(v, 8, 64);
            psum[i][r] = v;
        }
    if (m16 == 0) {
        #pragma unroll
        for (int i = 0; i < 4; ++i)
            #pragma unroll
            for (int r = 0; r < 4; ++r)
                sumP[w*64 + i*16 + q4*4 + r] = psum[i][r];
    }
    __syncthreads();
    if (t < 64) {
        float s = sumP[t] + sumP[64+t] + sumP[128+t] + sumP[192+t];
        float iv = 1.0f / fmaxf(s, 1e-30f);
        inv_s[t] = iv;
        if (q0 + t < T_) invA[(size_t)bh*T_ + q0 + t] = iv;
    }
    __syncthreads();

    // O epilogue: normalize + store x1 (bf16)
    {
        const int b = bh >> 3, h = bh & 7;
        #pragma unroll
        for (int j = 0; j < 4; ++j) {
            int d = j*16 + m16;
            #pragma unroll
            for (int r = 0; r < 4; ++r) {
                int rr = w*16 + q4*4 + r;
                int qg = q0 + rr;
                if (qg < T_)
                    x1b[((size_t)b*T_ + qg)*512 + h*64 + d] = f2bf(Oacc[j][r] * inv_s[rr]);
            }
        }
    }
}

// ---------------------------------------------------------------------------
// Expand packed bf16 e-row (prefix of each fr row) to normalized fp32 row.
// One block per row; __syncthreads separates all loads from all stores.
// ---------------------------------------------------------------------------
__global__ __launch_bounds__(256) void normalize_fr(
    float* __restrict__ fr, const float* __restrict__ invA)
{
    const int row = blockIdx.x;
    const int t = threadIdx.x;
    float* rowp = fr + (size_t)row * T_;
    const ushort* packed = (const ushort*)rowp;
    const float iv = invA[row];
    float v0 = bf2f(packed[t])       * iv;
    float v1 = bf2f(packed[t + 256]) * iv;
    float v2 = bf2f(packed[t + 512]) * iv;
    float v3 = 0.f;
    if (t == 0) v3 = bf2f(packed[768]) * iv;
    __syncthreads();
    rowp[t]       = v0;
    rowp[t + 256] = v1;
    rowp[t + 512] = v2;
    if (t == 0) rowp[768] = v3;
}

// ---------------------------------------------------------------------------
extern "C" void kernel_launch(void* const* d_in, const int* in_sizes, int n_in,
                              void* d_out, int out_size, void* d_ws, size_t ws_size,
                              hipStream_t stream)
{
    (void)in_sizes; (void)n_in; (void)out_size; (void)ws_size;
    const float* x_head   = (const float*)d_in[0];
    const float* x_tail   = (const float*)d_in[1];
    const int*   ids      = (const int*)  d_in[2];
    const float* W_head_w = (const float*)d_in[3];
    const float* W_head_b = (const float*)d_in[4];
    const float* W_v_w    = (const float*)d_in[5];
    const float* W_v_b    = (const float*)d_in[6];
    const float* W_out_w  = (const float*)d_in[7];
    const float* W_out_b  = (const float*)d_in[8];
    const float* rel      = (const float*)d_in[9];
    const float* col_h    = (const float*)d_in[10];
    const float* col_t    = (const float*)d_in[11];
    const float* biasp    = (const float*)d_in[12];

    const size_t F   = (size_t)BH_*T_*64;       // 3,149,824
    const size_t C22 = (size_t)BH_*T_*DCOL_;

    char* ws = (char*)d_ws;
    ushort* fhb = (ushort*)ws;   ws += F*2;
    ushort* ftb = (ushort*)ws;   ws += F*2;
    ushort* fvb = (ushort*)ws;   ws += F*2;
    ushort* x1b = (ushort*)ws;   ws += F*2;
    float*  chg = (float*)ws;    ws += C22*4;
    float*  ctg = (float*)ws;    ws += C22*4;
    float*  invA = (float*)ws;   ws += (size_t)BH_*T_*4;

    float* xout = (float*)d_out;
    float* fr   = xout + (size_t)BT_*D_;

    dim3 blk(256, 1, 1);

    gather_norm<<<(2*BH_*T_ + 255)/256, blk, 0, stream>>>(col_h, col_t, ids, chg, ctg);

    proj_mfma<<<dim3(4, 49, 3), blk, 0, stream>>>(
        x_head, x_tail, nullptr, W_head_w, W_v_w, W_out_w,
        W_head_b, W_v_b, W_out_b, rel, fhb, ftb, fvb, nullptr, -1);

    fused_attn<<<dim3(13, BH_), blk, 0, stream>>>(
        fhb, ftb, fvb, chg, ctg, biasp, fr, x1b, invA);

    normalize_fr<<<BH_*T_, blk, 0, stream>>>(fr, invA);

    proj_mfma<<<dim3(4, 49, 1), blk, 0, stream>>>(
        x_head, x_tail, x1b, W_head_w, W_v_w, W_out_w,
        W_head_b, W_v_b, W_out_b, rel, fhb, ftb, fvb, xout, 3);
}